// Round 11
// baseline (41.908 us; speedup 1.0000x reference)
//
#include <hip/hip_runtime.h>

typedef _Float16 f16x8 __attribute__((ext_vector_type(8)));
typedef float f32x4 __attribute__((ext_vector_type(4)));

__device__ __forceinline__ f16x8 splat8(float v) {
  _Float16 h = (_Float16)v;
  return f16x8{h, h, h, h, h, h, h, h};
}

// XOR swizzle on f16-index for row-stride-64 tiles: spread 16-row column reads
// across 8 bank groups. Involution; 16B-chunk granular; buffer offsets that are
// multiples of 8 rows (512 halves) don't disturb the row&7 bits used.
__device__ __forceinline__ int swzh(int i) { return i ^ (((i >> 6) & 7) << 3); }

// ------- Kernel 1: x NCHW f32 -> xt NHWC f16 (1024 blks) + weight prep (216 blks) -------
__global__ __launch_bounds__(256) void k_xtprep(const float* __restrict__ x,
                                                const float* __restrict__ wt,
                                                const float* __restrict__ ow,
                                                _Float16* __restrict__ xt,
                                                _Float16* __restrict__ wb,
                                                _Float16* __restrict__ owb) {
  __shared__ float tile[64 * 65];
  int blk = blockIdx.x;
  int t = threadIdx.x;
  if (blk < 1024) {
    int b = blk >> 8;
    int y = (blk >> 1) & 127;
    int w0 = (blk & 1) * 64;
    const float* xp = x + ((size_t)(b * 64) * 128 + y) * 128 + w0;
#pragma unroll
    for (int it = 0; it < 4; ++it) {
      int idx = it * 256 + t;
      int c = idx >> 4, q = idx & 15;
      float4 v = *(const float4*)(xp + (size_t)c * 16384 + q * 4);
      float* tp = &tile[c * 65 + q * 4];
      tp[0] = v.x; tp[1] = v.y; tp[2] = v.z; tp[3] = v.w;
    }
    __syncthreads();
#pragma unroll
    for (int it = 0; it < 2; ++it) {
      int idx = it * 256 + t;
      int w = idx >> 3, c8 = idx & 7;
      f16x8 o;
#pragma unroll
      for (int j = 0; j < 8; ++j) o[j] = (_Float16)tile[(c8 * 8 + j) * 65 + w];
      *(f16x8*)&xt[(((size_t)b * 128 + y) * 128 + w0 + w) * 64 + c8 * 8] = o;
    }
  } else {
    int i = (blk - 1024) * 256 + t;
    if (i < 36864) {
      int k = i >> 12, rem = i & 4095, o = rem >> 6, c = rem & 63;
      wb[i] = (_Float16)wt[(o * 64 + c) * 9 + k];
    } else if (i < 36864 + 18432) {
      int j = i - 36864;
      int k = j >> 11, rem = j & 2047, o = rem >> 6, c = rem & 63;
      float v = (o < 18) ? ow[(o * 64 + c) * 9 + k] : 0.0f;
      owb[j] = (_Float16)v;
    }
  }
}

// ---------------- Kernel 2: fused deformable conv, dbuf + swizzle ----------------
// grid 1024 = (2 wtiles of 64px) x (128 h) x (4 b), XCD-chunk swizzled; 256 thr.
// Phase A (R10): Xs-staged input, owb dbuf-staged (swz), 1 bar/tap.
// Phase B: dbuf S+Wk (swz, unpadded): per tap {issue k+1 loads; MFMA(k) from
//   LDS; interp+write k+1; 1 bar}. Staging latency hides under MFMA.
__global__ __launch_bounds__(256, 4) void k_fused(
    const _Float16* __restrict__ xt, const _Float16* __restrict__ wb,
    const _Float16* __restrict__ owb, const float* __restrict__ ob,
    const float* __restrict__ bias, float* __restrict__ out) {
  // LDS (40960 B total = 4 blocks/CU):
  //  [0..16384)    Sb: 2 x [64][64] f16, swizzled        (Phase B)
  //  [16384..32768) Wp: 2 x [64][64] f16, swizzled       (Phase B)
  //  [0..28512)    Xs: [198][72] f16 (aliases Sb+Wp)     (Phase A)
  //  [32768..40960) owbp: 2 x [32][64] f16, swizzled     (Phase A)
  //  [32768..37888) offL: [64][20] f32 (aliases owbp; written at Phase A end)
  __shared__ char lds[40960];
  _Float16* Sb = (_Float16*)lds;
  _Float16* Wp = (_Float16*)(lds + 16384);
  _Float16* Xs = (_Float16*)lds;
  _Float16* owbp = (_Float16*)(lds + 32768);
  float* offL = (float*)(lds + 32768);

  int t = threadIdx.x;
  int lb = (blockIdx.x & 7) * 128 + (blockIdx.x >> 3);  // 1024 = 8 XCDs x 128
  int w0 = (lb & 1) * 64;
  int h = (lb >> 1) & 127;
  int b = lb >> 8;

  int lane = t & 63, wid = t >> 6;
  int row = lane & 15, quad = lane >> 4;
  const _Float16* xb = xt + (size_t)b * 128 * 128 * 64;

  // ======= Stage0: Xs (rows h-1..h+1, px w0-1..w0+64, 64c) + owb tap0 =======
#pragma unroll
  for (int it = 0; it < 8; ++it) {
    int idx8 = it * 256 + t;  // 1584 Xs chunks + 256 owb chunks
    if (idx8 < 1584) {
      int c8 = idx8 & 7;
      int jr = idx8 >> 3;  // 0..197
      int jj = jr % 66;
      int ki = jr / 66;
      int gy = h - 1 + ki;
      int gx = w0 - 1 + jj;
      f16x8 v = {};
      if (((unsigned)gy < 128u) & ((unsigned)gx < 128u))
        v = *(const f16x8*)(xb + ((size_t)gy * 128 + gx) * 64 + c8 * 8);
      *(f16x8*)&Xs[(ki * 66 + jj) * 72 + c8 * 8] = v;
    } else if (idx8 < 1840) {
      int j = idx8 - 1584;  // owb tap 0 -> owbp buf0, swizzled
      int o = j >> 3, c8 = j & 7;
      *(f16x8*)&owbp[swzh(o * 64 + c8 * 8)] = *(const f16x8*)(owb + j * 8);
    }
  }
  __syncthreads();

  // ======= Phase A: offset conv, A from owbp (dbuf, swz), B from Xs =======
  {
    int woA = (wid >> 1) * 16;
    int wpA = (wid & 1) * 32;
    f32x4 accA[2];
    accA[0] = f32x4{0.f, 0.f, 0.f, 0.f};
    accA[1] = f32x4{0.f, 0.f, 0.f, 0.f};
#pragma unroll
    for (int k = 0; k < 9; ++k) {
      if (k < 8) {  // stage owb tap k+1 -> other buffer
        int o = t >> 3, c8 = t & 7;
        f16x8 v = *(const f16x8*)(owb + (k + 1) * 2048 + t * 8);
        *(f16x8*)&owbp[swzh(((k + 1) & 1) * 2048 + o * 64 + c8 * 8)] = v;
      }
      int ki = k / 3, kj = k % 3;
      int ai = (k & 1) * 2048 + (woA + row) * 64 + quad * 8;
      f16x8 afr0 = *(const f16x8*)&owbp[swzh(ai)];
      f16x8 afr1 = *(const f16x8*)&owbp[swzh(ai + 32)];
#pragma unroll
      for (int n = 0; n < 2; ++n) {
        int j = wpA + n * 16 + row + kj;  // 0..65
        const _Float16* lp = &Xs[(ki * 66 + j) * 72 + quad * 8];
        f16x8 b0 = *(const f16x8*)(lp);
        f16x8 b1 = *(const f16x8*)(lp + 32);
        accA[n] = __builtin_amdgcn_mfma_f32_16x16x32_f16(afr0, b0, accA[n], 0, 0, 0);
        accA[n] = __builtin_amdgcn_mfma_f32_16x16x32_f16(afr1, b1, accA[n], 0, 0, 0);
      }
      __syncthreads();
    }
    // offL aliases owbp; all owbp reads completed before tap-8's barrier.
    int qr = quad * 4;
#pragma unroll
    for (int n = 0; n < 2; ++n) {
#pragma unroll
      for (int r = 0; r < 4; ++r) {
        int co = woA + qr + r;
        if (co < 18)
          offL[(wpA + n * 16 + row) * 20 + co] = accA[n][r] + ob[co];
      }
    }
  }
  __syncthreads();  // offL visible; Xs dead -> Sb/Wp may be written

  // ======= Phase B: dbuf pipelined {issue; MFMA; finish; bar} =======
  int pix = t >> 2, cg = t & 3;
  int w = w0 + pix;
  int woB = (wid >> 1) * 32, wpB = (wid & 1) * 32;

  f16x8 wk0, wk1, ga0, ga1, gb0, gb1, gc0, gc1, gd0, gd1;
  float w00, w01, w10, w11;

#define SAMPLE_ISSUE(KK)                                                     \
  {                                                                          \
    float dy = offL[pix * 20 + 2 * (KK)];                                    \
    float dx = offL[pix * 20 + 2 * (KK) + 1];                                \
    float py = dy + (float)(h + (KK) / 3 - 1);                               \
    float pxf = dx + (float)(w + (KK) % 3 - 1);                              \
    float fy = floorf(py), fx = floorf(pxf);                                 \
    float ly = py - fy, lx = pxf - fx;                                       \
    int y0 = (int)fy, x0 = (int)fx;                                          \
    int y1 = y0 + 1, x1 = x0 + 1;                                            \
    bool vy0 = (unsigned)y0 < 128u, vy1 = (unsigned)y1 < 128u;               \
    bool vx0 = (unsigned)x0 < 128u, vx1 = (unsigned)x1 < 128u;               \
    w00 = (vy0 && vx0) ? (1.f - ly) * (1.f - lx) : 0.f;                      \
    w01 = (vy0 && vx1) ? (1.f - ly) * lx : 0.f;                              \
    w10 = (vy1 && vx0) ? ly * (1.f - lx) : 0.f;                              \
    w11 = (vy1 && vx1) ? ly * lx : 0.f;                                      \
    int yc0 = min(max(y0, 0), 127), yc1 = min(max(y1, 0), 127);              \
    int xc0 = min(max(x0, 0), 127), xc1 = min(max(x1, 0), 127);              \
    const _Float16* p00 = xb + (yc0 * 128 + xc0) * 64 + cg * 16;             \
    int dxo = (xc1 - xc0) * 64, dyo = (yc1 - yc0) * 8192;                    \
    ga0 = *(const f16x8*)(p00);                                              \
    ga1 = *(const f16x8*)(p00 + 8);                                          \
    gb0 = *(const f16x8*)(p00 + dxo);                                        \
    gb1 = *(const f16x8*)(p00 + dxo + 8);                                    \
    gc0 = *(const f16x8*)(p00 + dyo);                                        \
    gc1 = *(const f16x8*)(p00 + dyo + 8);                                    \
    gd0 = *(const f16x8*)(p00 + dyo + dxo);                                  \
    gd1 = *(const f16x8*)(p00 + dyo + dxo + 8);                              \
  }

#define SAMPLE_FINISH(DSTBUF)                                                \
  {                                                                          \
    f16x8 W00 = splat8(w00), W01 = splat8(w01);                              \
    f16x8 W10 = splat8(w10), W11 = splat8(w11);                              \
    f16x8 s0 = W00 * ga0 + W01 * gb0 + W10 * gc0 + W11 * gd0;                \
    f16x8 s1 = W00 * ga1 + W01 * gb1 + W10 * gc1 + W11 * gd1;                \
    int si = (DSTBUF) * 4096 + pix * 64 + cg * 16;                           \
    *(f16x8*)&Sb[swzh(si)] = s0;                                             \
    *(f16x8*)&Sb[swzh(si + 8)] = s1;                                         \
  }

  f32x4 acc[2][2];
#pragma unroll
  for (int i = 0; i < 2; ++i)
#pragma unroll
    for (int j = 0; j < 2; ++j) acc[i][j] = f32x4{0.f, 0.f, 0.f, 0.f};

  // prologue: tap 0 -> buffers 0
  {
    const f16x8* wsrc = (const f16x8*)wb;
    wk0 = wsrc[t];
    wk1 = wsrc[256 + t];
    SAMPLE_ISSUE(0)
    SAMPLE_FINISH(0)
    int wi = (t >> 3) * 64 + (t & 7) * 8;
    *(f16x8*)&Wp[swzh(wi)] = wk0;
    *(f16x8*)&Wp[swzh(wi + 2048)] = wk1;
  }
  __syncthreads();

#pragma unroll
  for (int k = 0; k < 9; ++k) {
    // ---- issue tap k+1 global loads (hide under MFMA below) ----
    if (k < 8) {
      const f16x8* wsrc = (const f16x8*)(wb + (k + 1) * 4096);
      wk0 = wsrc[t];
      wk1 = wsrc[256 + t];
      SAMPLE_ISSUE(k + 1)
    }
    // ---- MFMA tap k: all operands from LDS buf[k&1] ----
    {
      int bufo = (k & 1) * 4096;
#pragma unroll
      for (int ks = 0; ks < 2; ++ks) {
        int c0 = ks * 32 + quad * 8;
        f16x8 afr[2], bfr[2];
#pragma unroll
        for (int mi = 0; mi < 2; ++mi)
          afr[mi] = *(const f16x8*)&Wp[swzh(bufo + (woB + mi * 16 + row) * 64 + c0)];
#pragma unroll
        for (int ni = 0; ni < 2; ++ni)
          bfr[ni] = *(const f16x8*)&Sb[swzh(bufo + (wpB + ni * 16 + row) * 64 + c0)];
#pragma unroll
        for (int mi = 0; mi < 2; ++mi)
#pragma unroll
          for (int ni = 0; ni < 2; ++ni)
            acc[mi][ni] = __builtin_amdgcn_mfma_f32_16x16x32_f16(
                afr[mi], bfr[ni], acc[mi][ni], 0, 0, 0);
      }
    }
    // ---- finish tap k+1: interp + LDS writes into buf[(k+1)&1] ----
    if (k < 8) {
      SAMPLE_FINISH((k + 1) & 1)
      int wi = ((k + 1) & 1) * 4096 + (t >> 3) * 64 + (t & 7) * 8;
      *(f16x8*)&Wp[swzh(wi)] = wk0;
      *(f16x8*)&Wp[swzh(wi + 2048)] = wk1;
      __syncthreads();
    }
  }
#undef SAMPLE_ISSUE
#undef SAMPLE_FINISH

  // ---- epilogue: col=lane&15 (pix), row=quad*4+r (o) ----
  {
    int col = lane & 15;
    int qr = quad * 4;
#pragma unroll
    for (int mi = 0; mi < 2; ++mi) {
#pragma unroll
      for (int ni = 0; ni < 2; ++ni) {
#pragma unroll
        for (int r = 0; r < 4; ++r) {
          int o = woB + mi * 16 + qr + r;
          int pw = w0 + wpB + ni * 16 + col;
          out[(((size_t)b * 64 + o) * 128 + h) * 128 + pw] = acc[mi][ni][r] + bias[o];
        }
      }
    }
  }
}

extern "C" void kernel_launch(void* const* d_in, const int* in_sizes, int n_in,
                              void* d_out, int out_size, void* d_ws,
                              size_t ws_size, hipStream_t stream) {
  const float* x = (const float*)d_in[0];       // (4,64,128,128)
  const float* ow = (const float*)d_in[1];      // (18,64,3,3)
  const float* ob = (const float*)d_in[2];      // (18,)
  const float* wt = (const float*)d_in[3];      // (64,64,3,3)
  const float* bias = (const float*)d_in[4];    // (64,)
  float* out = (float*)d_out;                   // (4,64,128,128)

  char* ws = (char*)d_ws;
  _Float16* xt = (_Float16*)ws;                      // 8,388,608 B
  _Float16* wb = (_Float16*)(ws + 8388608);          // 73,728 B
  _Float16* owb = (_Float16*)(ws + 8388608 + 73728); // 36,864 B

  k_xtprep<<<1240, 256, 0, stream>>>(x, wt, ow, xt, wb, owb);
  k_fused<<<1024, 256, 0, stream>>>(xt, wb, owb, ob, bias, out);
}